// Round 13
// baseline (248.870 us; speedup 1.0000x reference)
//
#include <hip/hip_runtime.h>

// Problem constants (B=4, S=4096, D=1024, H=16, dh=64, WIN=256, STRIDE=128, nw=31)
#define SEQ 4096
#define DIM 1024
#define NWIN 31
#define NHEAD 16
#define NT 16  // K-steps of 64 in DIM=1024

typedef __attribute__((ext_vector_type(8))) short bf16x8;
typedef __attribute__((ext_vector_type(4))) float f32x4;

#define MFMA(a, b, c) __builtin_amdgcn_mfma_f32_16x16x32_bf16((a), (b), (c), 0, 0, 0)

__device__ __forceinline__ unsigned short f2bf(float f) {
  union { float f; unsigned u; } v; v.f = f;
  unsigned r = v.u + 0x7FFFu + ((v.u >> 16) & 1u);
  return (unsigned short)(r >> 16);
}
__device__ __forceinline__ float bf2f(unsigned short h) {
  union { unsigned u; float f; } v; v.u = ((unsigned)h) << 16;
  return v.f;
}
// packed f32x2 -> bf16x2 (RNE): dst lo16 = bf16(lo), dst hi16 = bf16(hi)
__device__ __forceinline__ unsigned cvtpk(float lo, float hi) {
  unsigned r;
  asm("v_cvt_pk_bf16_f32 %0, %1, %2" : "=v"(r) : "v"(lo), "v"(hi));
  return r;
}
// packed bf16x2 + bf16x2 via f32 adds + RNE repack
__device__ __forceinline__ unsigned addbf2(unsigned x, unsigned y) {
  union { unsigned u; float f; } a, b, c, d;
  a.u = x << 16; b.u = x & 0xffff0000u;
  c.u = y << 16; d.u = y & 0xffff0000u;
  return cvtpk(a.f + c.f, b.f + d.f);
}

// async global->LDS, 16B per lane. LDS dest = wave-uniform base + lane*16.
__device__ __forceinline__ void gll16(const void* g, void* l) {
  __builtin_amdgcn_global_load_lds((const __attribute__((address_space(1))) unsigned*)g,
                                   (__attribute__((address_space(3))) unsigned*)l,
                                   16, 0, 0);
}

// ---------------- prep: cast_x + tcast_w + zero_ctxb in ONE dispatch ----------------

__global__ __launch_bounds__(256) void prep_k(const float* __restrict__ X,
                                              const float* __restrict__ W0, const float* __restrict__ W1,
                                              const float* __restrict__ W2, const float* __restrict__ W3,
                                              unsigned short* __restrict__ Xb,
                                              unsigned short* __restrict__ Wt3,
                                              unsigned short* __restrict__ WoT,
                                              unsigned short* __restrict__ ctxB) {
  __shared__ float tile[64][65];
  const int bid = blockIdx.x;
  const int tid = threadIdx.x;

  if (bid < 8192) {
    // ---- cast X -> bf16 ----
    size_t i = ((size_t)bid * 256 + tid) * 8;
    float4 a = *(const float4*)(X + i);
    float4 b = *(const float4*)(X + i + 4);
    union { unsigned short u[8]; uint4 v; } pk;
    pk.u[0] = f2bf(a.x); pk.u[1] = f2bf(a.y); pk.u[2] = f2bf(a.z); pk.u[3] = f2bf(a.w);
    pk.u[4] = f2bf(b.x); pk.u[5] = f2bf(b.y); pk.u[6] = f2bf(b.z); pk.u[7] = f2bf(b.w);
    *(uint4*)(Xb + i) = pk.v;
  } else if (bid < 9216) {
    // ---- weight transpose + cast (Wq scaled by log2(e)/8) ----
    const int wb = bid - 8192;
    const int mat = wb >> 8;
    const int t = wb & 255;
    const int tr = (t >> 4) * 64, tc = (t & 15) * 64;
    const float* W = (mat == 0) ? W0 : (mat == 1) ? W1 : (mat == 2) ? W2 : W3;
    unsigned short* out = (mat < 3) ? (Wt3 + (size_t)mat * 1024 * 1024) : WoT;
    const float fscale = (mat == 0) ? 0.18033688011112042f : 1.0f;
    const int rr = tid >> 4, cc = (tid & 15) << 2;
#pragma unroll
    for (int i = 0; i < 4; ++i) {
      int r = i * 16 + rr;
      float4 v = *(const float4*)(W + (size_t)(tr + r) * DIM + tc + cc);
      tile[r][cc] = v.x; tile[r][cc + 1] = v.y; tile[r][cc + 2] = v.z; tile[r][cc + 3] = v.w;
    }
    __syncthreads();
#pragma unroll
    for (int i = 0; i < 4; ++i) {
      int orow = i * 16 + rr;
      union { unsigned short u[4]; uint2 v; } pk;
#pragma unroll
      for (int j = 0; j < 4; ++j) pk.u[j] = f2bf(tile[cc + j][orow] * fscale);
      *(uint2*)(out + (size_t)(tc + orow) * DIM + tr + cc) = pk.v;
    }
  } else {
    // ---- zero ctxB strips ----
    int gtid = (bid - 9216) * 256 + tid;
    int idx = gtid * 8;
    int srow = idx >> 10;
    int b = srow >> 8;
    int r = srow & 255;
    int seqrow = b * SEQ + ((r < 128) ? r : (3840 + r));
    uint4 z = {0, 0, 0, 0};
    *(uint4*)(ctxB + (size_t)seqrow * DIM + (idx & 1023)) = z;
  }
}

// ---------------- shared staging helper (bf16 panel, gll16) ----------------

__device__ __forceinline__ void stage_half(const unsigned short* __restrict__ src,
                                           int row0, int kcol0, char* slot, int tid) {
  const int w = tid >> 6;
  const int r0 = tid >> 2;          // rows 0..127 (o=0), +128 (o=1)
  const int c = (((tid & 3) ^ ((tid >> 3) & 3))) * 8;  // pre-swizzled source column
  gll16(src + (size_t)(row0 + r0) * DIM + kcol0 + c, slot + w * 1024);
  gll16(src + (size_t)(row0 + 128 + r0) * DIM + kcol0 + c, slot + 8192 + w * 1024);
}

// ---------------- 256x256 8-wave pipelined GEMM core (r9-proven, frozen) ----------------

__device__ __forceinline__ void gemm256_core(const unsigned short* __restrict__ A,
                                             const unsigned short* __restrict__ Bt,
                                             int m0, int n0, char* lds,
                                             f32x4 acc[8][4], int tid) {
  const int lane = tid & 63, w = tid >> 6;
  const int wm = w >> 2, wn = w & 3;
  const int l15 = lane & 15, g = lane >> 4;
  const int gs = g ^ ((l15 >> 1) & 3);  // swizzled chunk index

#define ASLOT(b, kk) (lds + ((b) * 2 + (kk)) * 16384)
#define BSLOT(b, kk) (lds + 65536 + ((b) * 2 + (kk)) * 16384)

  const int aoff = (wm * 128 + l15) * 64 + gs * 16;
  const int boff = (wn * 64 + l15) * 64 + gs * 16;

  stage_half(A,  m0, 0,  ASLOT(0, 0), tid);
  stage_half(Bt, n0, 0,  BSLOT(0, 0), tid);
  stage_half(A,  m0, 32, ASLOT(0, 1), tid);
  stage_half(Bt, n0, 32, BSLOT(0, 1), tid);
  stage_half(A,  m0, 64, ASLOT(1, 0), tid);
  stage_half(Bt, n0, 64, BSLOT(1, 0), tid);
  asm volatile("s_waitcnt vmcnt(8)" ::: "memory");
  __builtin_amdgcn_s_barrier();

  for (int s = 0; s < NT; ++s) {
    const int b = s & 1, nb = b ^ 1;
    const int k1 = (s + 1 < NT ? s + 1 : NT - 1) * 64;
    const int k2 = (s + 2 < NT ? s + 2 : NT - 1) * 64;
    char* Ab0 = ASLOT(b, 0); char* Ab1 = ASLOT(b, 1);
    char* Bb0 = BSLOT(b, 0); char* Bb1 = BSLOT(b, 1);
    bf16x8 af[8], bq0, bq1;

    // ===== phase 0 (kk0, qn0): stage A[nb][kk1] <- step s+1 =====
#pragma unroll
    for (int mt = 0; mt < 8; ++mt) af[mt] = *(const bf16x8*)(Ab0 + aoff + mt * 1024);
    bq0 = *(const bf16x8*)(Bb0 + boff);
    bq1 = *(const bf16x8*)(Bb0 + boff + 1024);
    stage_half(A, m0, k1 + 32, ASLOT(nb, 1), tid);
    __builtin_amdgcn_s_barrier();
    __builtin_amdgcn_s_setprio(1);
#pragma unroll
    for (int mt = 0; mt < 8; ++mt) {
      acc[mt][0] = MFMA(af[mt], bq0, acc[mt][0]);
      acc[mt][1] = MFMA(af[mt], bq1, acc[mt][1]);
    }
    __builtin_amdgcn_s_setprio(0);

    // ===== phase 1 (kk0, qn1): stage B[nb][kk1] <- step s+1, vmcnt =====
    bq0 = *(const bf16x8*)(Bb0 + boff + 2048);
    bq1 = *(const bf16x8*)(Bb0 + boff + 3072);
    stage_half(Bt, n0, k1 + 32, BSLOT(nb, 1), tid);
    asm volatile("s_waitcnt vmcnt(8)" ::: "memory");
    __builtin_amdgcn_s_barrier();
    __builtin_amdgcn_s_setprio(1);
#pragma unroll
    for (int mt = 0; mt < 8; ++mt) {
      acc[mt][2] = MFMA(af[mt], bq0, acc[mt][2]);
      acc[mt][3] = MFMA(af[mt], bq1, acc[mt][3]);
    }
    __builtin_amdgcn_s_setprio(0);

    // ===== phase 2 (kk1, qn0): stage A[b][kk0] <- step s+2 =====
#pragma unroll
    for (int mt = 0; mt < 8; ++mt) af[mt] = *(const bf16x8*)(Ab1 + aoff + mt * 1024);
    bq0 = *(const bf16x8*)(Bb1 + boff);
    bq1 = *(const bf16x8*)(Bb1 + boff + 1024);
    stage_half(A, m0, k2, ASLOT(b, 0), tid);
    __builtin_amdgcn_s_barrier();
    __builtin_amdgcn_s_setprio(1);
#pragma unroll
    for (int mt = 0; mt < 8; ++mt) {
      acc[mt][0] = MFMA(af[mt], bq0, acc[mt][0]);
      acc[mt][1] = MFMA(af[mt], bq1, acc[mt][1]);
    }
    __builtin_amdgcn_s_setprio(0);

    // ===== phase 3 (kk1, qn1): stage B[b][kk0] <- step s+2, vmcnt =====
    bq0 = *(const bf16x8*)(Bb1 + boff + 2048);
    bq1 = *(const bf16x8*)(Bb1 + boff + 3072);
    stage_half(Bt, n0, k2, BSLOT(b, 0), tid);
    asm volatile("s_waitcnt vmcnt(8)" ::: "memory");
    __builtin_amdgcn_s_barrier();
    __builtin_amdgcn_s_setprio(1);
#pragma unroll
    for (int mt = 0; mt < 8; ++mt) {
      acc[mt][2] = MFMA(af[mt], bq0, acc[mt][2]);
      acc[mt][3] = MFMA(af[mt], bq1, acc[mt][3]);
    }
    __builtin_amdgcn_s_setprio(0);
  }
#undef ASLOT
#undef BSLOT
}

// ---------------- fused-sum variant: A-half = bf16(ctxA+ctxB), reg-staged (r9, frozen) ----------------

struct AR { uint4 a0, b0, a1, b1; };

__device__ __forceinline__ void issueA(const unsigned short* __restrict__ cA,
                                       const unsigned short* __restrict__ cB,
                                       int row0, int kcol0, int tid, AR& r) {
  const int r0 = tid >> 2;
  const int c = (((tid & 3) ^ ((tid >> 3) & 3))) * 8;
  const size_t o1 = (size_t)(row0 + r0) * DIM + kcol0 + c;
  const size_t o2 = (size_t)(row0 + 128 + r0) * DIM + kcol0 + c;
  r.a0 = *(const uint4*)(cA + o1);
  r.b0 = *(const uint4*)(cB + o1);
  r.a1 = *(const uint4*)(cA + o2);
  r.b1 = *(const uint4*)(cB + o2);
}

__device__ __forceinline__ void writeA(char* slot, int tid, const AR& r) {
  uint4 lo, hi;
  lo.x = addbf2(r.a0.x, r.b0.x); lo.y = addbf2(r.a0.y, r.b0.y);
  lo.z = addbf2(r.a0.z, r.b0.z); lo.w = addbf2(r.a0.w, r.b0.w);
  hi.x = addbf2(r.a1.x, r.b1.x); hi.y = addbf2(r.a1.y, r.b1.y);
  hi.z = addbf2(r.a1.z, r.b1.z); hi.w = addbf2(r.a1.w, r.b1.w);
  *(uint4*)(slot + tid * 16) = lo;
  *(uint4*)(slot + 8192 + tid * 16) = hi;
}

__device__ __forceinline__ void gemm256_core_sum(const unsigned short* __restrict__ cA,
                                                 const unsigned short* __restrict__ cB,
                                                 const unsigned short* __restrict__ Bt,
                                                 int m0, int n0, char* lds,
                                                 f32x4 acc[8][4], int tid) {
  const int lane = tid & 63, w = tid >> 6;
  const int wm = w >> 2, wn = w & 3;
  const int l15 = lane & 15, g = lane >> 4;
  const int gs = g ^ ((l15 >> 1) & 3);

#define ASLOT(b, kk) (lds + ((b) * 2 + (kk)) * 16384)
#define BSLOT(b, kk) (lds + 65536 + ((b) * 2 + (kk)) * 16384)

  const int aoff = (wm * 128 + l15) * 64 + gs * 16;
  const int boff = (wn * 64 + l15) * 64 + gs * 16;

  AR R0, R1;
  issueA(cA, cB, m0, 0, tid, R0);  writeA(ASLOT(0, 0), tid, R0);
  issueA(cA, cB, m0, 32, tid, R0); writeA(ASLOT(0, 1), tid, R0);
  issueA(cA, cB, m0, 64, tid, R0); writeA(ASLOT(1, 0), tid, R0);
  stage_half(Bt, n0, 0,  BSLOT(0, 0), tid);
  stage_half(Bt, n0, 32, BSLOT(0, 1), tid);
  stage_half(Bt, n0, 64, BSLOT(1, 0), tid);
  issueA(cA, cB, m0, 96, tid, R1);
  asm volatile("s_waitcnt vmcnt(8)" ::: "memory");
  asm volatile("s_waitcnt lgkmcnt(0)" ::: "memory");
  __builtin_amdgcn_s_barrier();

  for (int s = 0; s < NT; ++s) {
    const int b = s & 1, nb = b ^ 1;
    const int k1 = (s + 1 < NT ? s + 1 : NT - 1) * 64;
    const int k2 = (s + 2 < NT ? s + 2 : NT - 1) * 64;
    char* Ab0 = ASLOT(b, 0); char* Ab1 = ASLOT(b, 1);
    char* Bb0 = BSLOT(b, 0); char* Bb1 = BSLOT(b, 1);
    bf16x8 af[8], bq0, bq1;
    (void)k1;

    // ===== phase 0: write A[nb][kk1] (<- R1), issue R0 <- A kk0 of s+2 =====
    writeA(ASLOT(nb, 1), tid, R1);
    asm volatile("s_waitcnt lgkmcnt(0)" ::: "memory");
    issueA(cA, cB, m0, k2, tid, R0);
#pragma unroll
    for (int mt = 0; mt < 8; ++mt) af[mt] = *(const bf16x8*)(Ab0 + aoff + mt * 1024);
    bq0 = *(const bf16x8*)(Bb0 + boff);
    bq1 = *(const bf16x8*)(Bb0 + boff + 1024);
    __builtin_amdgcn_s_barrier();
    __builtin_amdgcn_s_setprio(1);
#pragma unroll
    for (int mt = 0; mt < 8; ++mt) {
      acc[mt][0] = MFMA(af[mt], bq0, acc[mt][0]);
      acc[mt][1] = MFMA(af[mt], bq1, acc[mt][1]);
    }
    __builtin_amdgcn_s_setprio(0);

    // ===== phase 1: stage B[nb][kk1] <- step s+1, vmcnt =====
    bq0 = *(const bf16x8*)(Bb0 + boff + 2048);
    bq1 = *(const bf16x8*)(Bb0 + boff + 3072);
    stage_half(Bt, n0, k1 + 32, BSLOT(nb, 1), tid);
    asm volatile("s_waitcnt vmcnt(8)" ::: "memory");
    __builtin_amdgcn_s_barrier();
    __builtin_amdgcn_s_setprio(1);
#pragma unroll
    for (int mt = 0; mt < 8; ++mt) {
      acc[mt][2] = MFMA(af[mt], bq0, acc[mt][2]);
      acc[mt][3] = MFMA(af[mt], bq1, acc[mt][3]);
    }
    __builtin_amdgcn_s_setprio(0);

    // ===== phase 2: write A[b][kk0] (<- R0), issue R1 <- A kk1 of s+2 =====
    writeA(ASLOT(b, 0), tid, R0);
    asm volatile("s_waitcnt lgkmcnt(0)" ::: "memory");
    issueA(cA, cB, m0, k2 + 32, tid, R1);
#pragma unroll
    for (int mt = 0; mt < 8; ++mt) af[mt] = *(const bf16x8*)(Ab1 + aoff + mt * 1024);
    bq0 = *(const bf16x8*)(Bb1 + boff);
    bq1 = *(const bf16x8*)(Bb1 + boff + 1024);
    __builtin_amdgcn_s_barrier();
    __builtin_amdgcn_s_setprio(1);
#pragma unroll
    for (int mt = 0; mt < 8; ++mt) {
      acc[mt][0] = MFMA(af[mt], bq0, acc[mt][0]);
      acc[mt][1] = MFMA(af[mt], bq1, acc[mt][1]);
    }
    __builtin_amdgcn_s_setprio(0);

    // ===== phase 3: stage B[b][kk0] <- step s+2, vmcnt =====
    bq0 = *(const bf16x8*)(Bb1 + boff + 2048);
    bq1 = *(const bf16x8*)(Bb1 + boff + 3072);
    stage_half(Bt, n0, k2, BSLOT(b, 0), tid);
    asm volatile("s_waitcnt vmcnt(8)" ::: "memory");
    __builtin_amdgcn_s_barrier();
    __builtin_amdgcn_s_setprio(1);
#pragma unroll
    for (int mt = 0; mt < 8; ++mt) {
      acc[mt][2] = MFMA(af[mt], bq0, acc[mt][2]);
      acc[mt][3] = MFMA(af[mt], bq1, acc[mt][3]);
    }
    __builtin_amdgcn_s_setprio(0);
  }
#undef ASLOT
#undef BSLOT
}

// ---------------- GEMM 1: [Q|K|V] = Xb @ W, V written transposed ----------------

__global__ __launch_bounds__(512, 2) void gemm_qkv_k(const unsigned short* __restrict__ Xb,
                                                     const unsigned short* __restrict__ Wt3,
                                                     unsigned short* __restrict__ Qb,
                                                     unsigned short* __restrict__ Kb,
                                                     unsigned short* __restrict__ Vt) {
  __shared__ char lds[131072];
  const int nwg = 768;  // 64 m-tiles * 12 n-tiles
  const int wg = blockIdx.x;
  const int swz = (wg & 7) * (nwg >> 3) + (wg >> 3);  // XCD-aware (768 % 8 == 0)
  const int mtile = swz / 12, ntile = swz % 12;       // n fast: A-panel L2 reuse
  const int m0 = mtile * 256, n0 = ntile * 256;
  const int tid = threadIdx.x;

  f32x4 acc[8][4] = {};
  gemm256_core(Xb, Wt3, m0, n0, lds, acc, tid);

  const int lane = tid & 63, w = tid >> 6;
  const int wm = w >> 2, wn = w & 3;
  const int l15 = lane & 15, g = lane >> 4;
  const int mg0 = m0 + wm * 128;
  const int ng0 = n0 + wn * 64;

  if (n0 < 2048) {
    unsigned short* O = (n0 < 1024) ? Qb : Kb;
    const int nb = (n0 < 1024) ? 0 : 1024;
#pragma unroll
    for (int mt = 0; mt < 8; ++mt)
#pragma unroll
      for (int nt = 0; nt < 4; ++nt) {
        int ng = ng0 + nt * 16 + l15 - nb;
        int mg = mg0 + mt * 16 + g * 4;
#pragma unroll
        for (int r = 0; r < 4; ++r)
          O[(size_t)(mg + r) * DIM + ng] = f2bf(acc[mt][nt][r]);
      }
  } else {
    // V: store transposed Vt[d_global][m]
#pragma unroll
    for (int mt = 0; mt < 8; ++mt)
#pragma unroll
      for (int nt = 0; nt < 4; ++nt) {
        int ng = ng0 + nt * 16 + l15 - 2048;
        int mg = mg0 + mt * 16 + g * 4;
        union { unsigned short u[4]; uint2 v; } pk;
#pragma unroll
        for (int r = 0; r < 4; ++r) pk.u[r] = f2bf(acc[mt][nt][r]);
        *(uint2*)(Vt + (size_t)ng * (4 * SEQ) + mg) = pk.v;
      }
  }
}

// ---------------- GEMM 2: out = ((ctxA+ctxB) @ Wo) * rowscale ----------------

__global__ __launch_bounds__(512, 2) void gemm_out_k(const unsigned short* __restrict__ cA,
                                                     const unsigned short* __restrict__ cB,
                                                     const unsigned short* __restrict__ WoT,
                                                     float* __restrict__ out) {
  __shared__ char lds[131072];
  const int nwg = 256;  // 64 m-tiles * 4 n-tiles
  const int wg = blockIdx.x;
  const int swz = (wg & 7) * (nwg >> 3) + (wg >> 3);
  const int mtile = swz >> 2, ntile = swz & 3;
  const int m0 = mtile * 256, n0 = ntile * 256;
  const int tid = threadIdx.x;

  f32x4 acc[8][4] = {};
  gemm256_core_sum(cA, cB, WoT, m0, n0, lds, acc, tid);

  const int lane = tid & 63, w = tid >> 6;
  const int wm = w >> 2, wn = w & 3;
  const int l15 = lane & 15, g = lane >> 4;
  const int mg0 = m0 + wm * 128;
  const int ng0 = n0 + wn * 64;
#pragma unroll
  for (int mt = 0; mt < 8; ++mt)
#pragma unroll
    for (int nt = 0; nt < 4; ++nt) {
      int ng = ng0 + nt * 16 + l15;
      int mg = mg0 + mt * 16 + g * 4;
#pragma unroll
      for (int r = 0; r < 4; ++r) {
        int m = mg + r;
        int s = m & (SEQ - 1);
        // count = 1 at edges (s<128 or s>=3968), else 2; 1e-8 vanishes in fp32
        float scl = (s < 128 || s >= SEQ - 128) ? 1.0f : 0.5f;
        out[(size_t)m * DIM + ng] = acc[mt][nt][r] * scl;
      }
    }
}

// ---------------- attention v5: split-wait staging (V hidden under kc=0 QK) ----------------
// Issue order: K gll16(4) -> Q loads(4) -> V gll16(4).
// vmcnt(4)+barrier: K (and Q) drained wave-wide, V's 4 still in flight ->
// run kc=0 QK^T + exp + pack (touches only Kls + qf regs).
// vmcnt(0)+barrier: V landed -> PV kc=0, then kc=1..3 (LDS read-only, no
// further barriers). Same counted-drain-before-consumer invariant as the
// proven GEMM cores.

__global__ __launch_bounds__(512, 4) void attn_k(const unsigned short* __restrict__ Qb,
                                                 const unsigned short* __restrict__ Kb,
                                                 const unsigned short* __restrict__ Vt,
                                                 unsigned short* __restrict__ ctxA,
                                                 unsigned short* __restrict__ ctxB) {
  __shared__ char Kls[32768];   // [256 k-rows][128B] chunk-swizzled
  __shared__ char Vls[32768];   // [64 d-rows][512B] chunk-swizzled

  const int bid = blockIdx.x;
  const int h = bid & 15;
  const int rem = bid >> 4;
  const int n = rem % NWIN;
  const int b = rem / NWIN;
  const int tid = threadIdx.x;
  const int lane = tid & 63;
  const int w = tid >> 6;
  const int l15 = lane & 15, g = lane >> 4;

  const size_t qkbase = ((size_t)b * SEQ + (size_t)n * 128) * DIM + h * 64;
  const int wdst = w * 1024;

  // ---- stage K: 256 rows x 128B, 4 gll16/thread, chunk ^= row&7 ----
  {
    const int kr0 = tid >> 3;
    const int ksc = ((tid & 7) ^ (kr0 & 7)) * 8;
    const unsigned short* kg = Kb + qkbase + (size_t)kr0 * DIM + ksc;
#pragma unroll
    for (int j = 0; j < 4; ++j)
      gll16(kg + (size_t)(64 * j) * DIM, Kls + 8192 * j + wdst);
  }

  // ---- Q fragments direct from global (issued between K and V) ----
  bf16x8 qf[2][2];
#pragma unroll
  for (int qt = 0; qt < 2; ++qt)
#pragma unroll
    for (int kf = 0; kf < 2; ++kf)
      qf[qt][kf] = *(const bf16x8*)(Qb + qkbase +
                                    (size_t)(w * 32 + qt * 16 + l15) * DIM + kf * 32 + g * 8);

  // ---- stage V^T: 64 rows x 512B, 4 gll16/thread ----
  {
    const int vr0 = tid >> 5;
    const int vsc = ((tid & 31) ^ (vr0 & 7)) * 8;
    const unsigned short* vg = Vt + (size_t)(h * 64 + vr0) * (4 * SEQ) +
                               (size_t)b * SEQ + n * 128 + vsc;
#pragma unroll
    for (int j = 0; j < 4; ++j)
      gll16(vg + (size_t)(16 * j) * (4 * SEQ), Vls + 8192 * j + wdst);
  }

  f32x4 acc[2][4] = {};   // acc[qt][dt]: ctx^T, q = qt*16+l15, d = dt*16+g*4+r
  f32x4 psv[2] = {};      // per-lane partial row sums
  union PAU { unsigned u[4]; bf16x8 v; };
  PAU pa[2][2];

#define QKPACK(kc_)                                                                     \
  {                                                                                     \
    f32x4 s0[4] = {}, s1[4] = {};                                                       \
    __builtin_amdgcn_s_setprio(1);                                                      \
    _Pragma("unroll")                                                                   \
    for (int kt = 0; kt < 4; ++kt) {                                                    \
      int row = (kc_) * 64 + kt * 16 + l15;                                             \
      bf16x8 k0 = *(const bf16x8*)(Kls + row * 128 + ((g ^ (row & 7)) << 4));           \
      bf16x8 k1 = *(const bf16x8*)(Kls + row * 128 + (((4 + g) ^ (row & 7)) << 4));     \
      s0[kt] = MFMA(k0, qf[0][0], s0[kt]);                                              \
      s0[kt] = MFMA(k1, qf[0][1], s0[kt]);                                              \
      s1[kt] = MFMA(k0, qf[1][0], s1[kt]);                                              \
      s1[kt] = MFMA(k1, qf[1][1], s1[kt]);                                              \
    }                                                                                   \
    __builtin_amdgcn_s_setprio(0);                                                      \
    _Pragma("unroll")                                                                   \
    for (int kt = 0; kt < 4; ++kt) {                                                    \
      _Pragma("unroll")                                                                 \
      for (int r = 0; r < 4; ++r) {                                                     \
        s0[kt][r] = exp2f(s0[kt][r]);                                                   \
        s1[kt][r] = exp2f(s1[kt][r]);                                                   \
      }                                                                                 \
      psv[0] += s0[kt];                                                                 \
      psv[1] += s1[kt];                                                                 \
    }                                                                                   \
    _Pragma("unroll")                                                                   \
    for (int c = 0; c < 2; ++c) {                                                       \
      pa[0][c].u[0] = cvtpk(s0[2 * c][0], s0[2 * c][1]);                                \
      pa[0][c].u[1] = cvtpk(s0[2 * c][2], s0[2 * c][3]);                                \
      pa[0][c].u[2] = cvtpk(s0[2 * c + 1][0], s0[2 * c + 1][1]);                        \
      pa[0][c].u[3] = cvtpk(s0[2 * c + 1][2], s0[2 * c + 1][3]);                        \
      pa[1][c].u[0] = cvtpk(s1[2 * c][0], s1[2 * c][1]);                                \
      pa[1][c].u[1] = cvtpk(s1[2 * c][2], s1[2 * c][3]);                                \
      pa[1][c].u[2] = cvtpk(s1[2 * c + 1][0], s1[2 * c + 1][1]);                        \
      pa[1][c].u[3] = cvtpk(s1[2 * c + 1][2], s1[2 * c + 1][3]);                        \
    }                                                                                   \
  }

#define PVSTEP(kc_)                                                                     \
  {                                                                                     \
    __builtin_amdgcn_s_setprio(1);                                                      \
    _Pragma("unroll")                                                                   \
    for (int c = 0; c < 2; ++c) {                                                       \
      _Pragma("unroll")                                                                 \
      for (int dt = 0; dt < 4; ++dt) {                                                  \
        int row = dt * 16 + l15;                                                        \
        int c16 = (kc_) * 8 + c * 4 + (g >> 1);                                         \
        int off = (g & 1) * 8;                                                          \
        union { uint2 u2[2]; bf16x8 v; } vv;                                            \
        vv.u2[0] = *(const uint2*)(Vls + row * 512 + ((c16 ^ (row & 7)) << 4) + off);   \
        vv.u2[1] = *(const uint2*)(Vls + row * 512 + (((c16 + 2) ^ (row & 7)) << 4) + off); \
        acc[0][dt] = MFMA(vv.v, pa[0][c].v, acc[0][dt]);                                \
        acc[1][dt] = MFMA(vv.v, pa[1][c].v, acc[1][dt]);                                \
      }                                                                                 \
    }                                                                                   \
    __builtin_amdgcn_s_setprio(0);                                                      \
  }

  // K (+Q) drained for every wave; V's 4 loads remain in flight
  asm volatile("s_waitcnt vmcnt(4)" ::: "memory");
  __builtin_amdgcn_s_barrier();

  QKPACK(0);           // overlaps V's staging latency

  asm volatile("s_waitcnt vmcnt(0)" ::: "memory");
  __builtin_amdgcn_s_barrier();

  PVSTEP(0);
#pragma unroll
  for (int kc = 1; kc < 4; ++kc) {
    QKPACK(kc);
    PVSTEP(kc);
  }
#undef QKPACK
#undef PVSTEP

  // ---- epilogue: single row-sum reduce, divide, packed 8B stores ----
  unsigned short* outb = (n & 1) ? ctxB : ctxA;
  const size_t obase = ((size_t)b * SEQ + (size_t)n * 128 + w * 32) * DIM + h * 64;
#pragma unroll
  for (int qt = 0; qt < 2; ++qt) {
    float ps = psv[qt][0] + psv[qt][1] + psv[qt][2] + psv[qt][3];
    ps += __shfl_xor(ps, 16);
    ps += __shfl_xor(ps, 32);
    float inv = 1.0f / ps;
#pragma unroll
    for (int dt = 0; dt < 4; ++dt) {
      union { unsigned short u[4]; uint2 v; } pk;
#pragma unroll
      for (int r = 0; r < 4; ++r) pk.u[r] = f2bf(acc[qt][dt][r] * inv);
      *(uint2*)(outb + obase + (size_t)(qt * 16 + l15) * DIM + dt * 16 + g * 4) = pk.v;
    }
  }
}

// ---------------- launch ----------------

extern "C" void kernel_launch(void* const* d_in, const int* in_sizes, int n_in,
                              void* d_out, int out_size, void* d_ws, size_t ws_size,
                              hipStream_t stream) {
  const float* X  = (const float*)d_in[0];
  const float* Wq = (const float*)d_in[1];
  const float* Wk = (const float*)d_in[2];
  const float* Wv = (const float*)d_in[3];
  const float* Wo = (const float*)d_in[4];
  float* out = (float*)d_out;

  char* ws = (char*)d_ws;
  const size_t SZ = (size_t)4 * SEQ * DIM * 2;  // 33,554,432 B (one bf16 [16384][1024])
  unsigned short* Xb   = (unsigned short*)(ws);
  unsigned short* Wt3  = (unsigned short*)(ws + SZ);         // [3072][1024]
  unsigned short* WoT  = (unsigned short*)(ws + SZ + 6291456);
  unsigned short* Qb   = (unsigned short*)(ws + SZ + 8388608);
  unsigned short* Kb   = (unsigned short*)(ws + 2 * SZ + 8388608);
  unsigned short* Vt   = (unsigned short*)(ws + 3 * SZ + 8388608);
  unsigned short* ctxA = (unsigned short*)(ws + 4 * SZ + 8388608);
  unsigned short* ctxB = (unsigned short*)(ws + 5 * SZ + 8388608);
  // total: 6*SZ + 8 MB = 209,715,200 B

  prep_k<<<9728, 256, 0, stream>>>(X, Wq, Wk, Wv, Wo, Xb, Wt3, WoT, ctxB);
  gemm_qkv_k<<<768, 512, 0, stream>>>(Xb, Wt3, Qb, Kb, Vt);
  attn_k<<<4 * NWIN * NHEAD, 512, 0, stream>>>(Qb, Kb, Vt, ctxA, ctxB);
  gemm_out_k<<<256, 512, 0, stream>>>(ctxA, ctxB, WoT, out);
}

// Round 14
// 244.196 us; speedup vs baseline: 1.0191x; 1.0191x over previous
//
#include <hip/hip_runtime.h>

// Problem constants (B=4, S=4096, D=1024, H=16, dh=64, WIN=256, STRIDE=128, nw=31)
#define SEQ 4096
#define DIM 1024
#define NWIN 31
#define NHEAD 16
#define NT 16  // K-steps of 64 in DIM=1024

typedef __attribute__((ext_vector_type(8))) short bf16x8;
typedef __attribute__((ext_vector_type(4))) float f32x4;

#define MFMA(a, b, c) __builtin_amdgcn_mfma_f32_16x16x32_bf16((a), (b), (c), 0, 0, 0)

__device__ __forceinline__ unsigned short f2bf(float f) {
  union { float f; unsigned u; } v; v.f = f;
  unsigned r = v.u + 0x7FFFu + ((v.u >> 16) & 1u);
  return (unsigned short)(r >> 16);
}
__device__ __forceinline__ float bf2f(unsigned short h) {
  union { unsigned u; float f; } v; v.u = ((unsigned)h) << 16;
  return v.f;
}
// packed f32x2 -> bf16x2 (RNE): dst lo16 = bf16(lo), dst hi16 = bf16(hi)
__device__ __forceinline__ unsigned cvtpk(float lo, float hi) {
  unsigned r;
  asm("v_cvt_pk_bf16_f32 %0, %1, %2" : "=v"(r) : "v"(lo), "v"(hi));
  return r;
}
// packed bf16x2 + bf16x2 via f32 adds + RNE repack
__device__ __forceinline__ unsigned addbf2(unsigned x, unsigned y) {
  union { unsigned u; float f; } a, b, c, d;
  a.u = x << 16; b.u = x & 0xffff0000u;
  c.u = y << 16; d.u = y & 0xffff0000u;
  return cvtpk(a.f + c.f, b.f + d.f);
}

// async global->LDS, 16B per lane. LDS dest = wave-uniform base + lane*16.
__device__ __forceinline__ void gll16(const void* g, void* l) {
  __builtin_amdgcn_global_load_lds((const __attribute__((address_space(1))) unsigned*)g,
                                   (__attribute__((address_space(3))) unsigned*)l,
                                   16, 0, 0);
}

// ---------------- prep: cast_x + tcast_w + zero_ctxb in ONE dispatch ----------------

__global__ __launch_bounds__(256) void prep_k(const float* __restrict__ X,
                                              const float* __restrict__ W0, const float* __restrict__ W1,
                                              const float* __restrict__ W2, const float* __restrict__ W3,
                                              unsigned short* __restrict__ Xb,
                                              unsigned short* __restrict__ Wt3,
                                              unsigned short* __restrict__ WoT,
                                              unsigned short* __restrict__ ctxB) {
  __shared__ float tile[64][65];
  const int bid = blockIdx.x;
  const int tid = threadIdx.x;

  if (bid < 8192) {
    // ---- cast X -> bf16 ----
    size_t i = ((size_t)bid * 256 + tid) * 8;
    float4 a = *(const float4*)(X + i);
    float4 b = *(const float4*)(X + i + 4);
    union { unsigned short u[8]; uint4 v; } pk;
    pk.u[0] = f2bf(a.x); pk.u[1] = f2bf(a.y); pk.u[2] = f2bf(a.z); pk.u[3] = f2bf(a.w);
    pk.u[4] = f2bf(b.x); pk.u[5] = f2bf(b.y); pk.u[6] = f2bf(b.z); pk.u[7] = f2bf(b.w);
    *(uint4*)(Xb + i) = pk.v;
  } else if (bid < 9216) {
    // ---- weight transpose + cast (Wq scaled by log2(e)/8) ----
    const int wb = bid - 8192;
    const int mat = wb >> 8;
    const int t = wb & 255;
    const int tr = (t >> 4) * 64, tc = (t & 15) * 64;
    const float* W = (mat == 0) ? W0 : (mat == 1) ? W1 : (mat == 2) ? W2 : W3;
    unsigned short* out = (mat < 3) ? (Wt3 + (size_t)mat * 1024 * 1024) : WoT;
    const float fscale = (mat == 0) ? 0.18033688011112042f : 1.0f;
    const int rr = tid >> 4, cc = (tid & 15) << 2;
#pragma unroll
    for (int i = 0; i < 4; ++i) {
      int r = i * 16 + rr;
      float4 v = *(const float4*)(W + (size_t)(tr + r) * DIM + tc + cc);
      tile[r][cc] = v.x; tile[r][cc + 1] = v.y; tile[r][cc + 2] = v.z; tile[r][cc + 3] = v.w;
    }
    __syncthreads();
#pragma unroll
    for (int i = 0; i < 4; ++i) {
      int orow = i * 16 + rr;
      union { unsigned short u[4]; uint2 v; } pk;
#pragma unroll
      for (int j = 0; j < 4; ++j) pk.u[j] = f2bf(tile[cc + j][orow] * fscale);
      *(uint2*)(out + (size_t)(tc + orow) * DIM + tr + cc) = pk.v;
    }
  } else {
    // ---- zero ctxB strips ----
    int gtid = (bid - 9216) * 256 + tid;
    int idx = gtid * 8;
    int srow = idx >> 10;
    int b = srow >> 8;
    int r = srow & 255;
    int seqrow = b * SEQ + ((r < 128) ? r : (3840 + r));
    uint4 z = {0, 0, 0, 0};
    *(uint4*)(ctxB + (size_t)seqrow * DIM + (idx & 1023)) = z;
  }
}

// ---------------- shared staging helper (bf16 panel, gll16) ----------------

__device__ __forceinline__ void stage_half(const unsigned short* __restrict__ src,
                                           int row0, int kcol0, char* slot, int tid) {
  const int w = tid >> 6;
  const int r0 = tid >> 2;          // rows 0..127 (o=0), +128 (o=1)
  const int c = (((tid & 3) ^ ((tid >> 3) & 3))) * 8;  // pre-swizzled source column
  gll16(src + (size_t)(row0 + r0) * DIM + kcol0 + c, slot + w * 1024);
  gll16(src + (size_t)(row0 + 128 + r0) * DIM + kcol0 + c, slot + 8192 + w * 1024);
}

// ---------------- 256x256 8-wave pipelined GEMM core (r9-proven, frozen) ----------------

__device__ __forceinline__ void gemm256_core(const unsigned short* __restrict__ A,
                                             const unsigned short* __restrict__ Bt,
                                             int m0, int n0, char* lds,
                                             f32x4 acc[8][4], int tid) {
  const int lane = tid & 63, w = tid >> 6;
  const int wm = w >> 2, wn = w & 3;
  const int l15 = lane & 15, g = lane >> 4;
  const int gs = g ^ ((l15 >> 1) & 3);  // swizzled chunk index

#define ASLOT(b, kk) (lds + ((b) * 2 + (kk)) * 16384)
#define BSLOT(b, kk) (lds + 65536 + ((b) * 2 + (kk)) * 16384)

  const int aoff = (wm * 128 + l15) * 64 + gs * 16;
  const int boff = (wn * 64 + l15) * 64 + gs * 16;

  stage_half(A,  m0, 0,  ASLOT(0, 0), tid);
  stage_half(Bt, n0, 0,  BSLOT(0, 0), tid);
  stage_half(A,  m0, 32, ASLOT(0, 1), tid);
  stage_half(Bt, n0, 32, BSLOT(0, 1), tid);
  stage_half(A,  m0, 64, ASLOT(1, 0), tid);
  stage_half(Bt, n0, 64, BSLOT(1, 0), tid);
  asm volatile("s_waitcnt vmcnt(8)" ::: "memory");
  __builtin_amdgcn_s_barrier();

  for (int s = 0; s < NT; ++s) {
    const int b = s & 1, nb = b ^ 1;
    const int k1 = (s + 1 < NT ? s + 1 : NT - 1) * 64;
    const int k2 = (s + 2 < NT ? s + 2 : NT - 1) * 64;
    char* Ab0 = ASLOT(b, 0); char* Ab1 = ASLOT(b, 1);
    char* Bb0 = BSLOT(b, 0); char* Bb1 = BSLOT(b, 1);
    bf16x8 af[8], bq0, bq1;

    // ===== phase 0 (kk0, qn0): stage A[nb][kk1] <- step s+1 =====
#pragma unroll
    for (int mt = 0; mt < 8; ++mt) af[mt] = *(const bf16x8*)(Ab0 + aoff + mt * 1024);
    bq0 = *(const bf16x8*)(Bb0 + boff);
    bq1 = *(const bf16x8*)(Bb0 + boff + 1024);
    stage_half(A, m0, k1 + 32, ASLOT(nb, 1), tid);
    __builtin_amdgcn_s_barrier();
    __builtin_amdgcn_s_setprio(1);
#pragma unroll
    for (int mt = 0; mt < 8; ++mt) {
      acc[mt][0] = MFMA(af[mt], bq0, acc[mt][0]);
      acc[mt][1] = MFMA(af[mt], bq1, acc[mt][1]);
    }
    __builtin_amdgcn_s_setprio(0);

    // ===== phase 1 (kk0, qn1): stage B[nb][kk1] <- step s+1, vmcnt =====
    bq0 = *(const bf16x8*)(Bb0 + boff + 2048);
    bq1 = *(const bf16x8*)(Bb0 + boff + 3072);
    stage_half(Bt, n0, k1 + 32, BSLOT(nb, 1), tid);
    asm volatile("s_waitcnt vmcnt(8)" ::: "memory");
    __builtin_amdgcn_s_barrier();
    __builtin_amdgcn_s_setprio(1);
#pragma unroll
    for (int mt = 0; mt < 8; ++mt) {
      acc[mt][2] = MFMA(af[mt], bq0, acc[mt][2]);
      acc[mt][3] = MFMA(af[mt], bq1, acc[mt][3]);
    }
    __builtin_amdgcn_s_setprio(0);

    // ===== phase 2 (kk1, qn0): stage A[b][kk0] <- step s+2 =====
#pragma unroll
    for (int mt = 0; mt < 8; ++mt) af[mt] = *(const bf16x8*)(Ab1 + aoff + mt * 1024);
    bq0 = *(const bf16x8*)(Bb1 + boff);
    bq1 = *(const bf16x8*)(Bb1 + boff + 1024);
    stage_half(A, m0, k2, ASLOT(b, 0), tid);
    __builtin_amdgcn_s_barrier();
    __builtin_amdgcn_s_setprio(1);
#pragma unroll
    for (int mt = 0; mt < 8; ++mt) {
      acc[mt][0] = MFMA(af[mt], bq0, acc[mt][0]);
      acc[mt][1] = MFMA(af[mt], bq1, acc[mt][1]);
    }
    __builtin_amdgcn_s_setprio(0);

    // ===== phase 3 (kk1, qn1): stage B[b][kk0] <- step s+2, vmcnt =====
    bq0 = *(const bf16x8*)(Bb1 + boff + 2048);
    bq1 = *(const bf16x8*)(Bb1 + boff + 3072);
    stage_half(Bt, n0, k2, BSLOT(b, 0), tid);
    asm volatile("s_waitcnt vmcnt(8)" ::: "memory");
    __builtin_amdgcn_s_barrier();
    __builtin_amdgcn_s_setprio(1);
#pragma unroll
    for (int mt = 0; mt < 8; ++mt) {
      acc[mt][2] = MFMA(af[mt], bq0, acc[mt][2]);
      acc[mt][3] = MFMA(af[mt], bq1, acc[mt][3]);
    }
    __builtin_amdgcn_s_setprio(0);
  }
#undef ASLOT
#undef BSLOT
}

// ---------------- fused-sum variant: A-half = bf16(ctxA+ctxB), reg-staged (r9, frozen) ----------------

struct AR { uint4 a0, b0, a1, b1; };

__device__ __forceinline__ void issueA(const unsigned short* __restrict__ cA,
                                       const unsigned short* __restrict__ cB,
                                       int row0, int kcol0, int tid, AR& r) {
  const int r0 = tid >> 2;
  const int c = (((tid & 3) ^ ((tid >> 3) & 3))) * 8;
  const size_t o1 = (size_t)(row0 + r0) * DIM + kcol0 + c;
  const size_t o2 = (size_t)(row0 + 128 + r0) * DIM + kcol0 + c;
  r.a0 = *(const uint4*)(cA + o1);
  r.b0 = *(const uint4*)(cB + o1);
  r.a1 = *(const uint4*)(cA + o2);
  r.b1 = *(const uint4*)(cB + o2);
}

__device__ __forceinline__ void writeA(char* slot, int tid, const AR& r) {
  uint4 lo, hi;
  lo.x = addbf2(r.a0.x, r.b0.x); lo.y = addbf2(r.a0.y, r.b0.y);
  lo.z = addbf2(r.a0.z, r.b0.z); lo.w = addbf2(r.a0.w, r.b0.w);
  hi.x = addbf2(r.a1.x, r.b1.x); hi.y = addbf2(r.a1.y, r.b1.y);
  hi.z = addbf2(r.a1.z, r.b1.z); hi.w = addbf2(r.a1.w, r.b1.w);
  *(uint4*)(slot + tid * 16) = lo;
  *(uint4*)(slot + 8192 + tid * 16) = hi;
}

__device__ __forceinline__ void gemm256_core_sum(const unsigned short* __restrict__ cA,
                                                 const unsigned short* __restrict__ cB,
                                                 const unsigned short* __restrict__ Bt,
                                                 int m0, int n0, char* lds,
                                                 f32x4 acc[8][4], int tid) {
  const int lane = tid & 63, w = tid >> 6;
  const int wm = w >> 2, wn = w & 3;
  const int l15 = lane & 15, g = lane >> 4;
  const int gs = g ^ ((l15 >> 1) & 3);

#define ASLOT(b, kk) (lds + ((b) * 2 + (kk)) * 16384)
#define BSLOT(b, kk) (lds + 65536 + ((b) * 2 + (kk)) * 16384)

  const int aoff = (wm * 128 + l15) * 64 + gs * 16;
  const int boff = (wn * 64 + l15) * 64 + gs * 16;

  AR R0, R1;
  issueA(cA, cB, m0, 0, tid, R0);  writeA(ASLOT(0, 0), tid, R0);
  issueA(cA, cB, m0, 32, tid, R0); writeA(ASLOT(0, 1), tid, R0);
  issueA(cA, cB, m0, 64, tid, R0); writeA(ASLOT(1, 0), tid, R0);
  stage_half(Bt, n0, 0,  BSLOT(0, 0), tid);
  stage_half(Bt, n0, 32, BSLOT(0, 1), tid);
  stage_half(Bt, n0, 64, BSLOT(1, 0), tid);
  issueA(cA, cB, m0, 96, tid, R1);
  asm volatile("s_waitcnt vmcnt(8)" ::: "memory");
  asm volatile("s_waitcnt lgkmcnt(0)" ::: "memory");
  __builtin_amdgcn_s_barrier();

  for (int s = 0; s < NT; ++s) {
    const int b = s & 1, nb = b ^ 1;
    const int k1 = (s + 1 < NT ? s + 1 : NT - 1) * 64;
    const int k2 = (s + 2 < NT ? s + 2 : NT - 1) * 64;
    char* Ab0 = ASLOT(b, 0); char* Ab1 = ASLOT(b, 1);
    char* Bb0 = BSLOT(b, 0); char* Bb1 = BSLOT(b, 1);
    bf16x8 af[8], bq0, bq1;
    (void)k1;

    // ===== phase 0: write A[nb][kk1] (<- R1), issue R0 <- A kk0 of s+2 =====
    writeA(ASLOT(nb, 1), tid, R1);
    asm volatile("s_waitcnt lgkmcnt(0)" ::: "memory");
    issueA(cA, cB, m0, k2, tid, R0);
#pragma unroll
    for (int mt = 0; mt < 8; ++mt) af[mt] = *(const bf16x8*)(Ab0 + aoff + mt * 1024);
    bq0 = *(const bf16x8*)(Bb0 + boff);
    bq1 = *(const bf16x8*)(Bb0 + boff + 1024);
    __builtin_amdgcn_s_barrier();
    __builtin_amdgcn_s_setprio(1);
#pragma unroll
    for (int mt = 0; mt < 8; ++mt) {
      acc[mt][0] = MFMA(af[mt], bq0, acc[mt][0]);
      acc[mt][1] = MFMA(af[mt], bq1, acc[mt][1]);
    }
    __builtin_amdgcn_s_setprio(0);

    // ===== phase 1: stage B[nb][kk1] <- step s+1, vmcnt =====
    bq0 = *(const bf16x8*)(Bb0 + boff + 2048);
    bq1 = *(const bf16x8*)(Bb0 + boff + 3072);
    stage_half(Bt, n0, k1 + 32, BSLOT(nb, 1), tid);
    asm volatile("s_waitcnt vmcnt(8)" ::: "memory");
    __builtin_amdgcn_s_barrier();
    __builtin_amdgcn_s_setprio(1);
#pragma unroll
    for (int mt = 0; mt < 8; ++mt) {
      acc[mt][2] = MFMA(af[mt], bq0, acc[mt][2]);
      acc[mt][3] = MFMA(af[mt], bq1, acc[mt][3]);
    }
    __builtin_amdgcn_s_setprio(0);

    // ===== phase 2: write A[b][kk0] (<- R0), issue R1 <- A kk1 of s+2 =====
    writeA(ASLOT(b, 0), tid, R0);
    asm volatile("s_waitcnt lgkmcnt(0)" ::: "memory");
    issueA(cA, cB, m0, k2 + 32, tid, R1);
#pragma unroll
    for (int mt = 0; mt < 8; ++mt) af[mt] = *(const bf16x8*)(Ab1 + aoff + mt * 1024);
    bq0 = *(const bf16x8*)(Bb1 + boff);
    bq1 = *(const bf16x8*)(Bb1 + boff + 1024);
    __builtin_amdgcn_s_barrier();
    __builtin_amdgcn_s_setprio(1);
#pragma unroll
    for (int mt = 0; mt < 8; ++mt) {
      acc[mt][0] = MFMA(af[mt], bq0, acc[mt][0]);
      acc[mt][1] = MFMA(af[mt], bq1, acc[mt][1]);
    }
    __builtin_amdgcn_s_setprio(0);

    // ===== phase 3: stage B[b][kk0] <- step s+2, vmcnt =====
    bq0 = *(const bf16x8*)(Bb1 + boff + 2048);
    bq1 = *(const bf16x8*)(Bb1 + boff + 3072);
    stage_half(Bt, n0, k2, BSLOT(b, 0), tid);
    asm volatile("s_waitcnt vmcnt(8)" ::: "memory");
    __builtin_amdgcn_s_barrier();
    __builtin_amdgcn_s_setprio(1);
#pragma unroll
    for (int mt = 0; mt < 8; ++mt) {
      acc[mt][2] = MFMA(af[mt], bq0, acc[mt][2]);
      acc[mt][3] = MFMA(af[mt], bq1, acc[mt][3]);
    }
    __builtin_amdgcn_s_setprio(0);
  }
#undef ASLOT
#undef BSLOT
}

// ---------------- GEMM 1: [Q|K|V] = Xb @ W, V written transposed ----------------

__global__ __launch_bounds__(512, 2) void gemm_qkv_k(const unsigned short* __restrict__ Xb,
                                                     const unsigned short* __restrict__ Wt3,
                                                     unsigned short* __restrict__ Qb,
                                                     unsigned short* __restrict__ Kb,
                                                     unsigned short* __restrict__ Vt) {
  __shared__ char lds[131072];
  const int nwg = 768;  // 64 m-tiles * 12 n-tiles
  const int wg = blockIdx.x;
  const int swz = (wg & 7) * (nwg >> 3) + (wg >> 3);  // XCD-aware (768 % 8 == 0)
  const int mtile = swz / 12, ntile = swz % 12;       // n fast: A-panel L2 reuse
  const int m0 = mtile * 256, n0 = ntile * 256;
  const int tid = threadIdx.x;

  f32x4 acc[8][4] = {};
  gemm256_core(Xb, Wt3, m0, n0, lds, acc, tid);

  const int lane = tid & 63, w = tid >> 6;
  const int wm = w >> 2, wn = w & 3;
  const int l15 = lane & 15, g = lane >> 4;
  const int mg0 = m0 + wm * 128;
  const int ng0 = n0 + wn * 64;

  if (n0 < 2048) {
    unsigned short* O = (n0 < 1024) ? Qb : Kb;
    const int nb = (n0 < 1024) ? 0 : 1024;
#pragma unroll
    for (int mt = 0; mt < 8; ++mt)
#pragma unroll
      for (int nt = 0; nt < 4; ++nt) {
        int ng = ng0 + nt * 16 + l15 - nb;
        int mg = mg0 + mt * 16 + g * 4;
#pragma unroll
        for (int r = 0; r < 4; ++r)
          O[(size_t)(mg + r) * DIM + ng] = f2bf(acc[mt][nt][r]);
      }
  } else {
    // V: store transposed Vt[d_global][m]
#pragma unroll
    for (int mt = 0; mt < 8; ++mt)
#pragma unroll
      for (int nt = 0; nt < 4; ++nt) {
        int ng = ng0 + nt * 16 + l15 - 2048;
        int mg = mg0 + mt * 16 + g * 4;
        union { unsigned short u[4]; uint2 v; } pk;
#pragma unroll
        for (int r = 0; r < 4; ++r) pk.u[r] = f2bf(acc[mt][nt][r]);
        *(uint2*)(Vt + (size_t)ng * (4 * SEQ) + mg) = pk.v;
      }
  }
}

// ---------------- GEMM 2: out = ((ctxA+ctxB) @ Wo) * rowscale ----------------

__global__ __launch_bounds__(512, 2) void gemm_out_k(const unsigned short* __restrict__ cA,
                                                     const unsigned short* __restrict__ cB,
                                                     const unsigned short* __restrict__ WoT,
                                                     float* __restrict__ out) {
  __shared__ char lds[131072];
  const int nwg = 256;  // 64 m-tiles * 4 n-tiles
  const int wg = blockIdx.x;
  const int swz = (wg & 7) * (nwg >> 3) + (wg >> 3);
  const int mtile = swz >> 2, ntile = swz & 3;
  const int m0 = mtile * 256, n0 = ntile * 256;
  const int tid = threadIdx.x;

  f32x4 acc[8][4] = {};
  gemm256_core_sum(cA, cB, WoT, m0, n0, lds, acc, tid);

  const int lane = tid & 63, w = tid >> 6;
  const int wm = w >> 2, wn = w & 3;
  const int l15 = lane & 15, g = lane >> 4;
  const int mg0 = m0 + wm * 128;
  const int ng0 = n0 + wn * 64;
#pragma unroll
  for (int mt = 0; mt < 8; ++mt)
#pragma unroll
    for (int nt = 0; nt < 4; ++nt) {
      int ng = ng0 + nt * 16 + l15;
      int mg = mg0 + mt * 16 + g * 4;
#pragma unroll
      for (int r = 0; r < 4; ++r) {
        int m = mg + r;
        int s = m & (SEQ - 1);
        // count = 1 at edges (s<128 or s>=3968), else 2; 1e-8 vanishes in fp32
        float scl = (s < 128 || s >= SEQ - 128) ? 1.0f : 0.5f;
        out[(size_t)m * DIM + ng] = acc[mt][nt][r] * scl;
      }
    }
}

// ---------------- attention v4 (+T5 setprio): no-max softmax, 8 waves (r12-proven) ----------------

__global__ __launch_bounds__(512, 4) void attn_k(const unsigned short* __restrict__ Qb,
                                                 const unsigned short* __restrict__ Kb,
                                                 const unsigned short* __restrict__ Vt,
                                                 unsigned short* __restrict__ ctxA,
                                                 unsigned short* __restrict__ ctxB) {
  __shared__ char Kls[32768];   // [256 k-rows][128B] chunk-swizzled
  __shared__ char Vls[32768];   // [64 d-rows][512B] chunk-swizzled

  const int bid = blockIdx.x;
  const int h = bid & 15;
  const int rem = bid >> 4;
  const int n = rem % NWIN;
  const int b = rem / NWIN;
  const int tid = threadIdx.x;
  const int lane = tid & 63;
  const int w = tid >> 6;
  const int l15 = lane & 15, g = lane >> 4;

  const size_t qkbase = ((size_t)b * SEQ + (size_t)n * 128) * DIM + h * 64;
  const int wdst = w * 1024;

  // ---- stage K: 256 rows x 128B, 4 gll16/thread, chunk ^= row&7 ----
  {
    const int kr0 = tid >> 3;
    const int ksc = ((tid & 7) ^ (kr0 & 7)) * 8;
    const unsigned short* kg = Kb + qkbase + (size_t)kr0 * DIM + ksc;
#pragma unroll
    for (int j = 0; j < 4; ++j)
      gll16(kg + (size_t)(64 * j) * DIM, Kls + 8192 * j + wdst);
  }
  // ---- stage V^T: 64 rows x 512B, 4 gll16/thread ----
  {
    const int vr0 = tid >> 5;
    const int vsc = ((tid & 31) ^ (vr0 & 7)) * 8;
    const unsigned short* vg = Vt + (size_t)(h * 64 + vr0) * (4 * SEQ) +
                               (size_t)b * SEQ + n * 128 + vsc;
#pragma unroll
    for (int j = 0; j < 4; ++j)
      gll16(vg + (size_t)(16 * j) * (4 * SEQ), Vls + 8192 * j + wdst);
  }

  // ---- Q fragments direct from global (q = l15, d = kf*32 + g*8 + j) ----
  bf16x8 qf[2][2];
#pragma unroll
  for (int qt = 0; qt < 2; ++qt)
#pragma unroll
    for (int kf = 0; kf < 2; ++kf)
      qf[qt][kf] = *(const bf16x8*)(Qb + qkbase +
                                    (size_t)(w * 32 + qt * 16 + l15) * DIM + kf * 32 + g * 8);

  __syncthreads();

  f32x4 acc[2][4] = {};   // acc[qt][dt]: ctx^T, q = qt*16+l15, d = dt*16+g*4+r
  f32x4 psv[2] = {};      // per-lane partial row sums

  for (int kc = 0; kc < 4; ++kc) {
    // QK^T for both q-tiles
    f32x4 s0[4] = {}, s1[4] = {};
    __builtin_amdgcn_s_setprio(1);
#pragma unroll
    for (int kt = 0; kt < 4; ++kt) {
      int row = kc * 64 + kt * 16 + l15;
      bf16x8 k0 = *(const bf16x8*)(Kls + row * 128 + ((g ^ (row & 7)) << 4));
      bf16x8 k1 = *(const bf16x8*)(Kls + row * 128 + (((4 + g) ^ (row & 7)) << 4));
      s0[kt] = MFMA(k0, qf[0][0], s0[kt]);
      s0[kt] = MFMA(k1, qf[0][1], s0[kt]);
      s1[kt] = MFMA(k0, qf[1][0], s1[kt]);
      s1[kt] = MFMA(k1, qf[1][1], s1[kt]);
    }
    __builtin_amdgcn_s_setprio(0);
    // p = exp2(s); accumulate row sums (no max, no rescale)
#pragma unroll
    for (int kt = 0; kt < 4; ++kt) {
#pragma unroll
      for (int r = 0; r < 4; ++r) {
        s0[kt][r] = exp2f(s0[kt][r]);
        s1[kt][r] = exp2f(s1[kt][r]);
      }
      psv[0] += s0[kt];
      psv[1] += s1[kt];
    }
    // pack P fragments (permuted k order = lane's own scores)
    union { unsigned u[4]; bf16x8 v; } pa[2][2];
#pragma unroll
    for (int c = 0; c < 2; ++c) {
      pa[0][c].u[0] = cvtpk(s0[2 * c][0], s0[2 * c][1]);
      pa[0][c].u[1] = cvtpk(s0[2 * c][2], s0[2 * c][3]);
      pa[0][c].u[2] = cvtpk(s0[2 * c + 1][0], s0[2 * c + 1][1]);
      pa[0][c].u[3] = cvtpk(s0[2 * c + 1][2], s0[2 * c + 1][3]);
      pa[1][c].u[0] = cvtpk(s1[2 * c][0], s1[2 * c][1]);
      pa[1][c].u[1] = cvtpk(s1[2 * c][2], s1[2 * c][3]);
      pa[1][c].u[2] = cvtpk(s1[2 * c + 1][0], s1[2 * c + 1][1]);
      pa[1][c].u[3] = cvtpk(s1[2 * c + 1][2], s1[2 * c + 1][3]);
    }
    // PV (V fragment read once, used by both q-tiles)
    __builtin_amdgcn_s_setprio(1);
#pragma unroll
    for (int c = 0; c < 2; ++c)
#pragma unroll
      for (int dt = 0; dt < 4; ++dt) {
        int row = dt * 16 + l15;
        int c16 = kc * 8 + c * 4 + (g >> 1);
        int off = (g & 1) * 8;
        union { uint2 u2[2]; bf16x8 v; } vv;
        vv.u2[0] = *(const uint2*)(Vls + row * 512 + ((c16 ^ (row & 7)) << 4) + off);
        vv.u2[1] = *(const uint2*)(Vls + row * 512 + (((c16 + 2) ^ (row & 7)) << 4) + off);
        acc[0][dt] = MFMA(vv.v, pa[0][c].v, acc[0][dt]);
        acc[1][dt] = MFMA(vv.v, pa[1][c].v, acc[1][dt]);
      }
    __builtin_amdgcn_s_setprio(0);
  }

  // ---- epilogue: single row-sum reduce, divide, packed 8B stores ----
  unsigned short* outb = (n & 1) ? ctxB : ctxA;
  const size_t obase = ((size_t)b * SEQ + (size_t)n * 128 + w * 32) * DIM + h * 64;
#pragma unroll
  for (int qt = 0; qt < 2; ++qt) {
    float ps = psv[qt][0] + psv[qt][1] + psv[qt][2] + psv[qt][3];
    ps += __shfl_xor(ps, 16);
    ps += __shfl_xor(ps, 32);
    float inv = 1.0f / ps;
#pragma unroll
    for (int dt = 0; dt < 4; ++dt) {
      union { unsigned short u[4]; uint2 v; } pk;
#pragma unroll
      for (int r = 0; r < 4; ++r) pk.u[r] = f2bf(acc[qt][dt][r] * inv);
      *(uint2*)(outb + obase + (size_t)(qt * 16 + l15) * DIM + dt * 16 + g * 4) = pk.v;
    }
  }
}

// ---------------- launch ----------------

extern "C" void kernel_launch(void* const* d_in, const int* in_sizes, int n_in,
                              void* d_out, int out_size, void* d_ws, size_t ws_size,
                              hipStream_t stream) {
  const float* X  = (const float*)d_in[0];
  const float* Wq = (const float*)d_in[1];
  const float* Wk = (const float*)d_in[2];
  const float* Wv = (const float*)d_in[3];
  const float* Wo = (const float*)d_in[4];
  float* out = (float*)d_out;

  char* ws = (char*)d_ws;
  const size_t SZ = (size_t)4 * SEQ * DIM * 2;  // 33,554,432 B (one bf16 [16384][1024])
  unsigned short* Xb   = (unsigned short*)(ws);
  unsigned short* Wt3  = (unsigned short*)(ws + SZ);         // [3072][1024]
  unsigned short* WoT  = (unsigned short*)(ws + SZ + 6291456);
  unsigned short* Qb   = (unsigned short*)(ws + SZ + 8388608);
  unsigned short* Kb   = (unsigned short*)(ws + 2 * SZ + 8388608);
  unsigned short* Vt   = (unsigned short*)(ws + 3 * SZ + 8388608);
  unsigned short* ctxA = (unsigned short*)(ws + 4 * SZ + 8388608);
  unsigned short* ctxB = (unsigned short*)(ws + 5 * SZ + 8388608);
  // total: 6*SZ + 8 MB = 209,715,200 B

  prep_k<<<9728, 256, 0, stream>>>(X, Wq, Wk, Wv, Wo, Xb, Wt3, WoT, ctxB);
  gemm_qkv_k<<<768, 512, 0, stream>>>(Xb, Wt3, Qb, Kb, Vt);
  attn_k<<<4 * NWIN * NHEAD, 512, 0, stream>>>(Qb, Kb, Vt, ctxA, ctxB);
  gemm_out_k<<<256, 512, 0, stream>>>(ctxA, ctxB, WoT, out);
}